// Round 16
// baseline (212.761 us; speedup 1.0000x reference)
//
#include <hip/hip_runtime.h>
#include <hip/hip_bf16.h>

#define B_ 4
#define S_ 2048
#define E_ 768
#define H_ 12
#define D_ 64
#define M_ (B_*S_)      // 8192
#define NQKV 2304
#define KDIM 768

typedef __bf16 bf16x8 __attribute__((ext_vector_type(8)));
typedef float f32x4 __attribute__((ext_vector_type(4)));
typedef short shortx4 __attribute__((ext_vector_type(4)));
typedef unsigned int uintx2 __attribute__((ext_vector_type(2)));
typedef unsigned int uintx4 __attribute__((ext_vector_type(4)));

typedef __attribute__((address_space(1))) void gvoid;
typedef __attribute__((address_space(3))) void lvoid;

__device__ __forceinline__ void gl_lds16(const void* g, void* l) {
  __builtin_amdgcn_global_load_lds((gvoid*)g, (lvoid*)l, 16, 0, 0);
}

__device__ __forceinline__ f32x4 mfma16(bf16x8 a, bf16x8 b, f32x4 c) {
  return __builtin_amdgcn_mfma_f32_16x16x32_bf16(a, b, c, 0, 0, 0);
}

// PV MFMA: 16x16 tile, K=16. A/B: 4 bf16/lane, k = quad*4 + elem.
__device__ __forceinline__ f32x4 mfma_pv(shortx4 a, shortx4 b, f32x4 c) {
#if __has_builtin(__builtin_amdgcn_mfma_f32_16x16x16bf16_1k)
  return __builtin_amdgcn_mfma_f32_16x16x16bf16_1k(a, b, c, 0, 0, 0);
#else
  uintx2 au = __builtin_bit_cast(uintx2, a);
  uintx2 bu = __builtin_bit_cast(uintx2, b);
  uintx4 aw = {au.x, au.y, 0u, 0u};
  uintx4 bw = {bu.x, bu.y, 0u, 0u};
  return mfma16(__builtin_bit_cast(bf16x8, aw), __builtin_bit_cast(bf16x8, bw), c);
#endif
}

// Load element idx from a buffer that is either bf16 (is_bf=1) or fp32 (is_bf=0).
__device__ __forceinline__ __bf16 ldmix(const void* p, size_t idx, int is_bf) {
  if (is_bf) return ((const __bf16*)p)[idx];
  return (__bf16)(((const float*)p)[idx]);
}
__device__ __forceinline__ float ldmixf(const void* p, size_t idx, int is_bf) {
  if (is_bf) return (float)((const __bf16*)p)[idx];
  return ((const float*)p)[idx];
}

// ---------------- merged prep: mask scan (blocks 0..3) + dtype self-detect +
// x->bf16 (blocks 4..3075) + LDS-TILED weight transpose (blocks 3076..3651)
// + biases (block 3652). (r15-measured WIN: coalesced tiled transpose.) ------
__global__ __launch_bounds__(256) void prep_kernel(
    const void* __restrict__ x, const int* __restrict__ mask,
    const void* __restrict__ Wq, const void* __restrict__ bq,
    const void* __restrict__ Wk, const void* __restrict__ bk,
    const void* __restrict__ Wv, const void* __restrict__ bv,
    const void* __restrict__ Wo, const void* __restrict__ bo,
    int* __restrict__ flag,
    __bf16* __restrict__ Xb,
    __bf16* __restrict__ WbT, __bf16* __restrict__ WoT,
    float* __restrict__ biasP, float* __restrict__ biasO,
    int* __restrict__ R, int* __restrict__ npadArr, int* __restrict__ narrArr)
{
  const int t = threadIdx.x;
  const int bid = blockIdx.x;

  if (bid < 4) {                          // mask scan for batch bid
    __shared__ int wtot[4];
    __shared__ int runningS;
    const int w = t >> 6, lane = t & 63;
    const int b = bid;
    if (t == 0) runningS = 0;
    __syncthreads();
    for (int k0 = 0; k0 < S_; k0 += 256) {
      int keep = (mask[b * S_ + k0 + t] != 0) ? 1 : 0;
      unsigned long long bal = __ballot(keep);
      int lanePre = __popcll(bal & ((1ull << lane) - 1ull));
      if (lane == 0) wtot[w] = __popcll(bal);
      __syncthreads();
      int base = runningS;
      for (int i = 0; i < w; ++i) base += wtot[i];
      if (keep) R[b * S_ + base + lanePre] = b * S_ + k0 + t;
      __syncthreads();
      if (t == 0) runningS += wtot[0] + wtot[1] + wtot[2] + wtot[3];
      __syncthreads();
    }
    int n = runningS;
    for (int j = n + t; j < S_; j += 256)   // pad FULL tail (safe gather rows)
      R[b * S_ + j] = b * S_;
    if (t == 0) { npadArr[b] = (n + 63) & ~63; narrArr[b] = n; }
    return;
  }

  // dtype self-detect: sample first 512 u16 of x (L1/L2-hot broadcast).
  __shared__ int scnt[4];
  {
    const unsigned short* xr = (const unsigned short*)x;
    unsigned short h = xr[2 * t];
    int e = (h >> 7) & 0xFF;
    unsigned long long bal = __ballot(e >= 100 && e <= 140);
    if ((t & 63) == 0) scnt[t >> 6] = __popcll(bal);
  }
  __syncthreads();
  const int is_bf = (scnt[0] + scnt[1] + scnt[2] + scnt[3] > 148) ? 1 : 0;
  if (bid == 4 && t == 0) *flag = is_bf;

  const int cb = bid - 4;
  if (cb < 3072) {                        // convx: 3072*256*8 = 6291456 elems
    int base = (cb * 256 + t) * 8;
    if (is_bf) {
      *(uintx4*)(Xb + base) = *(const uintx4*)((const __bf16*)x + base);
    } else {
      const float* xf = (const float*)x + base;
      f32x4 a = *(const f32x4*)xf;
      f32x4 c = *(const f32x4*)(xf + 4);
      __bf16 ov[8] = {(__bf16)a[0], (__bf16)a[1], (__bf16)a[2], (__bf16)a[3],
                      (__bf16)c[0], (__bf16)c[1], (__bf16)c[2], (__bf16)c[3]};
      *(uintx4*)(Xb + base) = *(uintx4*)ov;
    }
    return;
  }

  const int tb = cb - 3072;               // transpose tile / bias block index
  if (tb >= 577) return;

  if (tb == 576) {                        // biases: 2304 + 768 = 3072 scalars
    for (int i = t; i < 3072; i += 256) {
      if (i < NQKV) {
        int sel = i / 768, hd = i - sel * 768;
        const void* bsel = (sel == 0) ? bq : (sel == 1) ? bk : bv;
        biasP[i] = ldmixf(bsel, hd, is_bf);
      } else {
        biasO[i - NQKV] = ldmixf(bo, i - NQKV, is_bf);
      }
    }
    return;
  }

  // 64x64 LDS-tiled transpose. tl row pad +2 keeps 4B bank granularity:
  // column reads alias 2 lanes/bank (free per m136).
  __shared__ __bf16 tl[64][66];
  const int er  = t >> 2;                 // 0..63: input row within tile
  const int cg  = (t & 3) * 16;           // 16-elem chunk within row

  const void* src;                        // input, row-major [rows][cols]
  size_t ibase; int istride;              // elem index = ibase + row*istride + col
  __bf16* dst; int n0, c0out;             // output rows n0+dr, cols c0out+ec
  if (tb < 432) {                         // WbT: transpose W[h] (768e x 64d)
    int combo = tb / 12;                  // 0..35 = sel*12+h
    int e0 = (tb - combo * 12) * 64;
    int sel = combo / 12, h = combo - sel * 12;
    src = (sel == 0) ? Wq : (sel == 1) ? Wk : Wv;
    ibase = (size_t)(h * 768 + e0) * 64;  // rows: e (stride 64), cols: d
    istride = 64;
    dst = WbT; n0 = sel * 768 + h * 64; c0out = e0;
  } else {                                // WoT: transpose Wo (768k x 768n)
    int tj = tb - 432;                    // 0..143
    int r0 = (tj / 12) * 64;              // output-row block (n of Wo)
    int c0 = (tj - (tj / 12) * 12) * 64;  // output-col block (k of Wo)
    src = Wo;
    ibase = (size_t)c0 * 768 + r0;        // rows: k (stride 768), cols: n
    istride = 768;
    dst = WoT; n0 = r0; c0out = c0;
  }

  {
    size_t off = ibase + (size_t)er * istride + cg;
    if (is_bf) {
      bf16x8 a = *(const bf16x8*)((const __bf16*)src + off);
      bf16x8 bvv = *(const bf16x8*)((const __bf16*)src + off + 8);
      *(bf16x8*)(&tl[er][cg]) = a;
      *(bf16x8*)(&tl[er][cg + 8]) = bvv;
    } else {
      const float* sf = (const float*)src + off;
      f32x4 a = *(const f32x4*)sf;
      f32x4 bvv = *(const f32x4*)(sf + 4);
      f32x4 c = *(const f32x4*)(sf + 8);
      f32x4 d = *(const f32x4*)(sf + 12);
      __bf16 cv[16] = {(__bf16)a[0], (__bf16)a[1], (__bf16)a[2], (__bf16)a[3],
                       (__bf16)bvv[0], (__bf16)bvv[1], (__bf16)bvv[2], (__bf16)bvv[3],
                       (__bf16)c[0], (__bf16)c[1], (__bf16)c[2], (__bf16)c[3],
                       (__bf16)d[0], (__bf16)d[1], (__bf16)d[2], (__bf16)d[3]};
      *(bf16x8*)(&tl[er][cg]) = *(bf16x8*)cv;
      *(bf16x8*)(&tl[er][cg + 8]) = *(bf16x8*)(cv + 8);
    }
  }
  __syncthreads();
  {
    const int dr = t >> 2;                // output row within tile
    const int ec = (t & 3) * 16;          // output col chunk
    __bf16 ov[16];
#pragma unroll
    for (int j = 0; j < 16; ++j) ov[j] = tl[ec + j][dr];
    __bf16* po = dst + (size_t)(n0 + dr) * 768 + c0out + ec;
    *(uintx4*)po = *(uintx4*)ov;
    *(uintx4*)(po + 8) = *(uintx4*)(ov + 8);
  }
}

// ---------------- fused Q + K/V projection, 128x128 tiles, DOUBLE-BUFFERED --
// r10 counters: 46.6us, MfmaUtil 16%, FETCH 64MB (HBM-priced staging loads,
// ~900cy), 24 K-steps each draining vmcnt(0) at ~4.5 blocks/CU TLP -> the
// barrier drain is the dominant cost and NOT hidden (unlike attn's L2-hit
// case). T3/T4 minimum 2-phase: stage tile k+1 (exactly 4 gl_lds16/thread),
// s_waitcnt vmcnt(4) (tile k complete, k+1 in flight), raw barriers.
__global__ __launch_bounds__(256) void gemm_qkv(
    const __bf16* __restrict__ Xb,    // [8192][768]
    const __bf16* __restrict__ WbT,   // [2304][768]
    const float* __restrict__ biasP,  // [2304]
    const int* __restrict__ R,        // [B][2048] fully padded
    const int* __restrict__ npadArr,  // [B]
    __bf16* __restrict__ Qc,          // [8192][768]
    __bf16* __restrict__ Kc,          // [48][2048][64]
    __bf16* __restrict__ Vc)          // [48][512][256]
{
  __shared__ __align__(16) __bf16 As[2][128 * 32];
  __shared__ __align__(16) __bf16 Bs[2][128 * 32];
  const int t = threadIdx.x;
  const int wave = t >> 6, lane = t & 63;
  const int l15 = lane & 15, lq = lane >> 4;
  const int wm = (wave & 1) * 64;
  const int wn = (wave >> 1) * 64;

  const int bid = blockIdx.x;
  int m0, bn0, isQ, b = 0;
  int rowA0, rowA1;
  if (bid < 384) {
    isQ = 1;
    int mi = bid / 6, ni = bid - mi * 6;
    m0 = mi * 128; bn0 = ni * 128;
    rowA0 = m0 + (t >> 2);
    rowA1 = m0 + 64 + (t >> 2);
  } else {
    isQ = 0;
    int r2 = bid - 384;
    b = r2 / 192;
    int rr = r2 - b * 192;
    int mi = rr / 12, ni = rr - mi * 12;
    int np = npadArr[b];
    np = (np < 0) ? 0 : ((np > 2048) ? 2048 : np);   // poison-safe
    if (mi * 128 >= np) return;
    m0 = mi * 128;
    bn0 = 768 + ni * 128;
    rowA0 = R[b * S_ + m0 + (t >> 2)] & (M_ - 1);    // poison-safe
    rowA1 = R[b * S_ + m0 + 64 + (t >> 2)] & (M_ - 1);
  }
  const int c8 = (t & 3) << 3;
  const int brow0 = bn0 + (t >> 2);
  const int brow1 = bn0 + 64 + (t >> 2);

  const f32x4 z4 = {0.f, 0.f, 0.f, 0.f};
  f32x4 acc[4][4];
#pragma unroll
  for (int i = 0; i < 4; ++i)
#pragma unroll
    for (int j = 0; j < 4; ++j) acc[i][j] = z4;

  // prologue: stage K-step 0 into buf 0
  gl_lds16(Xb + (size_t)rowA0 * KDIM + c8, As[0] + (size_t)wave * 512);
  gl_lds16(Xb + (size_t)rowA1 * KDIM + c8, As[0] + (size_t)(2048 + wave * 512));
  gl_lds16(WbT + (size_t)brow0 * KDIM + c8, Bs[0] + (size_t)wave * 512);
  gl_lds16(WbT + (size_t)brow1 * KDIM + c8, Bs[0] + (size_t)(2048 + wave * 512));

  const int NK = KDIM / 32;   // 24
  for (int ki = 0; ki < NK; ++ki) {
    const int cur = ki & 1;
    if (ki + 1 < NK) {                 // stage next tile into buf cur^1
      const int nxt = cur ^ 1;
      const int k1 = (ki + 1) * 32;
      gl_lds16(Xb + (size_t)rowA0 * KDIM + k1 + c8, As[nxt] + (size_t)wave * 512);
      gl_lds16(Xb + (size_t)rowA1 * KDIM + k1 + c8, As[nxt] + (size_t)(2048 + wave * 512));
      gl_lds16(WbT + (size_t)brow0 * KDIM + k1 + c8, Bs[nxt] + (size_t)wave * 512);
      gl_lds16(WbT + (size_t)brow1 * KDIM + k1 + c8, Bs[nxt] + (size_t)(2048 + wave * 512));
      asm volatile("s_waitcnt vmcnt(4)" ::: "memory");  // tile cur done, nxt in flight
    } else {
      asm volatile("s_waitcnt vmcnt(0)" ::: "memory");
    }
    __builtin_amdgcn_s_barrier();

    const __bf16* Ab = As[cur];
    const __bf16* Bb = Bs[cur];
    bf16x8 af[4], bfr[4];
#pragma unroll
    for (int i = 0; i < 4; ++i) af[i]  = *(const bf16x8*)(Ab + (wm + i * 16 + l15) * 32 + lq * 8);
#pragma unroll
    for (int j = 0; j < 4; ++j) bfr[j] = *(const bf16x8*)(Bb + (wn + j * 16 + l15) * 32 + lq * 8);
#pragma unroll
    for (int i = 0; i < 4; ++i)
#pragma unroll
      for (int j = 0; j < 4; ++j)
        acc[i][j] = mfma16(af[i], bfr[j], acc[i][j]);

    __builtin_amdgcn_s_barrier();      // all waves done with buf[cur] before
                                       // iter ki+1 stages into it
  }

#pragma unroll
  for (int j = 0; j < 4; ++j) {
    if (isQ) {
      int nn = bn0 + wn + j * 16 + l15;
      float bv = biasP[nn];
#pragma unroll
      for (int i = 0; i < 4; ++i) {
        int mbase = m0 + wm + i * 16 + lq * 4;
#pragma unroll
        for (int r = 0; r < 4; ++r)
          Qc[(size_t)(mbase + r) * 768 + nn] = (__bf16)(acc[i][j][r] + bv);
      }
    } else {
      int nn = (bn0 - 768) + wn + j * 16 + l15;   // col within 1536
      float bv = biasP[768 + nn];
      const int isK = (nn < 768);
      const int hh = (isK ? nn : nn - 768) >> 6;
      const int d  = nn & 63;
      const size_t bhh = (size_t)(b * H_ + hh);
#pragma unroll
      for (int i = 0; i < 4; ++i) {
        int jbase = m0 + wm + i * 16 + lq * 4;
#pragma unroll
        for (int r = 0; r < 4; ++r) {
          int jj = jbase + r;
          __bf16 ov = (__bf16)(acc[i][j][r] + bv);
          if (isK) Kc[(bhh * 2048 + jj) * 64 + d] = ov;
          else     Vc[(bhh * 512 + (jj >> 2)) * 256 + d * 4 + (jj & 3)] = ov;
        }
      }
    }
  }
}

// ---------------- output projection, 128x128 tiles (384 blocks) ----------------
__global__ __launch_bounds__(256) void gemm_out(
    const __bf16* __restrict__ A,     // [8192][768] attn out
    const __bf16* __restrict__ WoT,   // [768][768]
    const float* __restrict__ biasO,  // [768]
    void* __restrict__ C,             // [8192][768] fp32 or bf16 per flag
    const int* __restrict__ flag)
{
  __shared__ __align__(16) __bf16 As[128 * 32];
  __shared__ __align__(16) __bf16 Bs[128 * 32];
  const int obf = *flag;
  const int t = threadIdx.x;
  const int wave = t >> 6, lane = t & 63;
  const int l15 = lane & 15, lq = lane >> 4;
  const int wm = (wave & 1) * 64;
  const int wn = (wave >> 1) * 64;
  const int m0 = blockIdx.x * 128;
  const int n0 = blockIdx.y * 128;
  const int c8 = (t & 3) << 3;
  const int rowA0 = m0 + (t >> 2);
  const int rowA1 = m0 + 64 + (t >> 2);
  const int brow0 = n0 + (t >> 2);
  const int brow1 = n0 + 64 + (t >> 2);

  const f32x4 z4 = {0.f, 0.f, 0.f, 0.f};
  f32x4 acc[4][4];
#pragma unroll
  for (int i = 0; i < 4; ++i)
#pragma unroll
    for (int j = 0; j < 4; ++j) acc[i][j] = z4;

  for (int k0 = 0; k0 < KDIM; k0 += 32) {
    __syncthreads();
    gl_lds16(A + (size_t)rowA0 * KDIM + k0 + c8, As + (size_t)wave * 512);
    gl_lds16(A + (size_t)rowA1 * KDIM + k0 + c8, As + (size_t)(2048 + wave * 512));
    gl_lds16(WoT + (size_t)brow0 * KDIM + k0 + c8, Bs + (size_t)wave * 512);
    gl_lds16(WoT + (size_t)brow1 * KDIM + k0 + c8, Bs + (size_t)(2048 + wave * 512));
    __syncthreads();
    bf16x8 af[4], bfr[4];
#pragma unroll
    for (int i = 0; i < 4; ++i) af[i]  = *(const bf16x8*)(As + (wm + i * 16 + l15) * 32 + lq * 8);
#pragma unroll
    for (int j = 0; j < 4; ++j) bfr[j] = *(const bf16x8*)(Bs + (wn + j * 16 + l15) * 32 + lq * 8);
#pragma unroll
    for (int i = 0; i < 4; ++i)
#pragma unroll
      for (int j = 0; j < 4; ++j)
        acc[i][j] = mfma16(af[i], bfr[j], acc[i][j]);
  }

#pragma unroll
  for (int j = 0; j < 4; ++j) {
    int n = n0 + wn + j * 16 + l15;
    float bv = biasO[n];
#pragma unroll
    for (int i = 0; i < 4; ++i) {
      int mbase = m0 + wm + i * 16 + lq * 4;
#pragma unroll
      for (int r = 0; r < 4; ++r) {
        size_t off = (size_t)(mbase + r) * 768 + n;
        float val = acc[i][j][r] + bv;
        if (obf) ((__bf16*)C)[off] = (__bf16)val;
        else     ((float*)C)[off]  = val;
      }
    }
  }
}

// ---------------- attention: round-8 best (QBLK=64, K/V LDS dbuf, counted
// vmcnt(4), swizzled K; 55.6us measured). --------------------------------
__global__ __launch_bounds__(256) void attn_kernel(
    const __bf16* __restrict__ Qc,     // [8192][768] (b,s,h,d)
    const __bf16* __restrict__ Kc,     // [48][2048][64]
    const __bf16* __restrict__ Vc,     // [48][512][256] quad layout
    const int* __restrict__ npadArr,   // [4] padded count
    const int* __restrict__ narrArr,   // [4] true count
    __bf16* __restrict__ Out)          // [8192][768] (b,s,h,d)
{
  __shared__ __align__(16) __bf16 Ks0[2][64 * 32];  // [buf][key][d 0..31] swz
  __shared__ __align__(16) __bf16 Ks1[2][64 * 32];  // [buf][key][d 32..63] swz
  __shared__ __align__(16) __bf16 Vt[2][16 * 256];  // [buf][key-quad][d][4 keys]

  const int t = threadIdx.x;
  const int w = t >> 6, lane = t & 63;
  const int l15 = lane & 15, qd = lane >> 4;
  const int bh = blockIdx.y;
  const int b = bh / H_, h = bh - b * H_;
  const int q0 = blockIdx.x * 64;
  int Skv = npadArr[b];
  Skv = (Skv < 0) ? 0 : ((Skv > 2048) ? 2048 : Skv);   // poison-safe
  int nb = narrArr[b];
  nb = (nb < 0) ? 0 : ((nb > Skv) ? Skv : nb);

  const __bf16* Qb = Qc + (size_t)b * S_ * E_ + h * 64;
  const __bf16* Kb = Kc + (size_t)bh * 2048 * 64;
  const __bf16* Vg = Vc + (size_t)bh * 512 * 256;

  bf16x8 qf[2];
  {
    int qrow = q0 + w * 16 + l15;
    qf[0] = *(const bf16x8*)(Qb + (size_t)qrow * E_ + qd * 8);
    qf[1] = *(const bf16x8*)(Qb + (size_t)qrow * E_ + 32 + qd * 8);
  }

  const f32x4 z4 = {0.f, 0.f, 0.f, 0.f};
  f32x4 o[4];
#pragma unroll
  for (int dt = 0; dt < 4; ++dt) o[dt] = z4;
  f32x4 ol = z4;

  const short one_bf = (short)0x3F80;
  const shortx4 ones4 = {one_bf, one_bf, one_bf, one_bf};

  const int skey = t >> 2;
  // source-side swizzle: chunk c_src = (t&3) ^ ((skey>>1)&3); skey>>1 = t>>3.
  const int sch  = (((t & 3) ^ ((t >> 3) & 3)) * 8);
  // read-side swizzle: chunk qd ^ ((l15>>1)&3), in elems (x8).
  const int qsw  = ((qd ^ ((l15 >> 1) & 3)) * 8);
  const float SC = 0.18033688011112042f;  // 0.125 * log2(e)

  const int nt = Skv >> 6;
  if (nt > 0) {
    gl_lds16(Kb + (size_t)skey * 64 + sch,      &Ks0[0][w * 512]);
    gl_lds16(Kb + (size_t)skey * 64 + 32 + sch, &Ks1[0][w * 512]);
    gl_lds16(Vg + t * 8,        &Vt[0][w * 512]);
    gl_lds16(Vg + 2048 + t * 8, &Vt[0][2048 + w * 512]);
  }

  for (int ti = 0; ti < nt; ++ti) {
    const int k0 = ti << 6;
    const int cur = ti & 1;
    if (ti + 1 < nt) {               // uniform branch (Skv uniform per block)
      const int nxt = cur ^ 1;
      const int kk = k0 + 64;
      gl_lds16(Kb + (size_t)(kk + skey) * 64 + sch,      &Ks0[nxt][w * 512]);
      gl_lds16(Kb + (size_t)(kk + skey) * 64 + 32 + sch, &Ks1[nxt][w * 512]);
      const __bf16* vsrc = Vg + ((size_t)(kk >> 2)) * 256;
      gl_lds16(vsrc + t * 8,        &Vt[nxt][w * 512]);
      gl_lds16(vsrc + 2048 + t * 8, &Vt[nxt][2048 + w * 512]);
      asm volatile("s_waitcnt vmcnt(4)" ::: "memory");  // tile cur done, nxt in flight
    } else {
      asm volatile("s_waitcnt vmcnt(0)" ::: "memory");
    }
    __builtin_amdgcn_s_barrier();

    const __bf16* K0 = Ks0[cur];
    const __bf16* K1 = Ks1[cur];
    const __bf16* Vb = Vt[cur];

    bf16x8 kf[4][2];
#pragma unroll
    for (int kt = 0; kt < 4; ++kt) {
      kf[kt][0] = *(const bf16x8*)(K0 + (kt * 16 + l15) * 32 + qsw);
      kf[kt][1] = *(const bf16x8*)(K1 + (kt * 16 + l15) * 32 + qsw);
    }
    shortx4 vf[4][4];
#pragma unroll
    for (int kt = 0; kt < 4; ++kt)
#pragma unroll
      for (int dt = 0; dt < 4; ++dt)
        vf[kt][dt] = *(const shortx4*)(Vb + (kt * 4 + qd) * 256 + (dt * 16 + l15) * 4);

    f32x4 ma[4];
    if (k0 + 64 <= nb) {             // all keys real: no mask (common path)
#pragma unroll
      for (int kt = 0; kt < 4; ++kt) ma[kt] = z4;
    } else {                         // boundary tile: pads start at nb
#pragma unroll
      for (int kt = 0; kt < 4; ++kt) {
        int kk = k0 + kt * 16 + qd * 4;
#pragma unroll
        for (int r = 0; r < 4; ++r)
          ma[kt][r] = (kk + r < nb) ? 0.f : -1.0e9f;
      }
    }

    {
      f32x4 s[4];
#pragma unroll
      for (int kt = 0; kt < 4; ++kt) {
        s[kt] = mfma16(kf[kt][0], qf[0], z4);
        s[kt] = mfma16(kf[kt][1], qf[1], s[kt]);
      }
      shortx4 pfr[4];
#pragma unroll
      for (int kt = 0; kt < 4; ++kt) {
        float p0 = __builtin_amdgcn_exp2f(__builtin_fmaf(s[kt][0], SC, ma[kt][0]));
        float p1 = __builtin_amdgcn_exp2f(__builtin_fmaf(s[kt][1], SC, ma[kt][1]));
        float p2 = __builtin_amdgcn_exp2f(__builtin_fmaf(s[kt][2], SC, ma[kt][2]));
        float p3 = __builtin_amdgcn_exp2f(__builtin_fmaf(s[kt][3], SC, ma[kt][3]));
        unsigned int lo16 = __builtin_amdgcn_perm(__builtin_bit_cast(unsigned int, p1),
                                                  __builtin_bit_cast(unsigned int, p0), 0x07060302u);
        unsigned int hi16 = __builtin_amdgcn_perm(__builtin_bit_cast(unsigned int, p3),
                                                  __builtin_bit_cast(unsigned int, p2), 0x07060302u);
        uintx2 u = {lo16, hi16};
        pfr[kt] = __builtin_bit_cast(shortx4, u);
      }
#pragma unroll
      for (int dt = 0; dt < 4; ++dt)
#pragma unroll
        for (int kt = 0; kt < 4; ++kt)
          o[dt] = mfma_pv(pfr[kt], vf[kt][dt], o[dt]);
#pragma unroll
      for (int kt = 0; kt < 4; ++kt)
        ol = mfma_pv(pfr[kt], ones4, ol);
    }

    __builtin_amdgcn_s_barrier();    // all waves done reading buf[cur] before
                                     // next iter's stage overwrites it
  }

#pragma unroll
  for (int dt = 0; dt < 4; ++dt)
#pragma unroll
    for (int r = 0; r < 4; ++r) {
      int qrow = q0 + w * 16 + qd * 4 + r;
      Out[(size_t)(b * S_ + qrow) * E_ + h * 64 + dt * 16 + l15] =
          (__bf16)(o[dt][r] / ol[r]);
    }
}

extern "C" void kernel_launch(void* const* d_in, const int* in_sizes, int n_in,
                              void* d_out, int out_size, void* d_ws, size_t ws_size,
                              hipStream_t stream) {
  const void* x  = d_in[0];
  const int* mask = (const int*)d_in[1];
  const void* Wq = d_in[2];
  const void* bq = d_in[3];
  const void* Wk = d_in[4];
  const void* bk = d_in[5];
  const void* Wv = d_in[6];
  const void* bv = d_in[7];
  const void* Wo = d_in[8];
  const void* bo = d_in[9];

  char* ws = (char*)d_ws;
  int*    flag  = (int*)(ws + 0);             // 256 B
  __bf16* Xb    = (__bf16*)(ws + 256);        // 12582912 -> 12583168
  __bf16* WbT   = (__bf16*)(ws + 12583168);   // 3538944  -> 16122112
  __bf16* WoT   = (__bf16*)(ws + 16122112);   // 1179648  -> 17301760
  float*  biasP = (float*)(ws + 17301760);    // 9216     -> 17310976
  float*  biasO = (float*)(ws + 17310976);    // 3072     -> 17314048
  __bf16* Qc    = (__bf16*)(ws + 17314048);   // 12582912 -> 29896960
  __bf16* Kc    = (__bf16*)(ws + 29896960);   // 12582912 -> 42479872
  __bf16* Vc    = (__bf16*)(ws + 42479872);   // 12582912 -> 55062784
  __bf16* attnO = (__bf16*)(ws + 55062784);   // 12582912 -> 67645696
  int*    Ridx  = (int*)(ws + 67645696);      // 32768    -> 67678464
  int*    npad  = (int*)(ws + 67711232);      // 16       -> 67711248
  int*    narr  = (int*)(ws + 67711248);      // 16       -> 67711264

  prep_kernel<<<dim3(3653), dim3(256), 0, stream>>>(
      x, mask, Wq, bq, Wk, bk, Wv, bv, Wo, bo,
      flag, Xb, WbT, WoT, biasP, biasO, Ridx, npad, narr);
  gemm_qkv<<<dim3(1152), dim3(256), 0, stream>>>(Xb, WbT, biasP, Ridx, npad, Qc, Kc, Vc);
  attn_kernel<<<dim3(32, 48), dim3(256), 0, stream>>>(Qc, Kc, Vc, npad, narr, attnO);
  gemm_out<<<dim3(64, 6), dim3(256), 0, stream>>>(attnO, WoT, biasO, d_out, flag);
}

// Round 20
// 206.059 us; speedup vs baseline: 1.0325x; 1.0325x over previous
//
#include <hip/hip_runtime.h>
#include <hip/hip_bf16.h>

#define B_ 4
#define S_ 2048
#define E_ 768
#define H_ 12
#define D_ 64
#define M_ (B_*S_)      // 8192
#define NQKV 2304
#define KDIM 768

typedef __bf16 bf16x8 __attribute__((ext_vector_type(8)));
typedef float f32x4 __attribute__((ext_vector_type(4)));
typedef short shortx4 __attribute__((ext_vector_type(4)));
typedef unsigned int uintx2 __attribute__((ext_vector_type(2)));
typedef unsigned int uintx4 __attribute__((ext_vector_type(4)));

typedef __attribute__((address_space(1))) void gvoid;
typedef __attribute__((address_space(3))) void lvoid;

__device__ __forceinline__ void gl_lds16(const void* g, void* l) {
  __builtin_amdgcn_global_load_lds((gvoid*)g, (lvoid*)l, 16, 0, 0);
}

__device__ __forceinline__ f32x4 mfma16(bf16x8 a, bf16x8 b, f32x4 c) {
  return __builtin_amdgcn_mfma_f32_16x16x32_bf16(a, b, c, 0, 0, 0);
}

// PV MFMA: 16x16 tile, K=16. A/B: 4 bf16/lane, k = quad*4 + elem.
__device__ __forceinline__ f32x4 mfma_pv(shortx4 a, shortx4 b, f32x4 c) {
#if __has_builtin(__builtin_amdgcn_mfma_f32_16x16x16bf16_1k)
  return __builtin_amdgcn_mfma_f32_16x16x16bf16_1k(a, b, c, 0, 0, 0);
#else
  uintx2 au = __builtin_bit_cast(uintx2, a);
  uintx2 bu = __builtin_bit_cast(uintx2, b);
  uintx4 aw = {au.x, au.y, 0u, 0u};
  uintx4 bw = {bu.x, bu.y, 0u, 0u};
  return mfma16(__builtin_bit_cast(bf16x8, aw), __builtin_bit_cast(bf16x8, bw), c);
#endif
}

// Load element idx from a buffer that is either bf16 (is_bf=1) or fp32 (is_bf=0).
__device__ __forceinline__ __bf16 ldmix(const void* p, size_t idx, int is_bf) {
  if (is_bf) return ((const __bf16*)p)[idx];
  return (__bf16)(((const float*)p)[idx]);
}
__device__ __forceinline__ float ldmixf(const void* p, size_t idx, int is_bf) {
  if (is_bf) return (float)((const __bf16*)p)[idx];
  return ((const float*)p)[idx];
}

// ---------------- merged prep: mask scan (blocks 0..3) + dtype self-detect +
// x->bf16 (blocks 4..3075) + LDS-TILED weight transpose (blocks 3076..3651)
// + biases (block 3652). (r15-measured WIN: coalesced tiled transpose.) ------
__global__ __launch_bounds__(256) void prep_kernel(
    const void* __restrict__ x, const int* __restrict__ mask,
    const void* __restrict__ Wq, const void* __restrict__ bq,
    const void* __restrict__ Wk, const void* __restrict__ bk,
    const void* __restrict__ Wv, const void* __restrict__ bv,
    const void* __restrict__ Wo, const void* __restrict__ bo,
    int* __restrict__ flag,
    __bf16* __restrict__ Xb,
    __bf16* __restrict__ WbT, __bf16* __restrict__ WoT,
    float* __restrict__ biasP, float* __restrict__ biasO,
    int* __restrict__ R, int* __restrict__ npadArr, int* __restrict__ narrArr)
{
  const int t = threadIdx.x;
  const int bid = blockIdx.x;

  if (bid < 4) {                          // mask scan for batch bid
    __shared__ int wtot[4];
    __shared__ int runningS;
    const int w = t >> 6, lane = t & 63;
    const int b = bid;
    if (t == 0) runningS = 0;
    __syncthreads();
    for (int k0 = 0; k0 < S_; k0 += 256) {
      int keep = (mask[b * S_ + k0 + t] != 0) ? 1 : 0;
      unsigned long long bal = __ballot(keep);
      int lanePre = __popcll(bal & ((1ull << lane) - 1ull));
      if (lane == 0) wtot[w] = __popcll(bal);
      __syncthreads();
      int base = runningS;
      for (int i = 0; i < w; ++i) base += wtot[i];
      if (keep) R[b * S_ + base + lanePre] = b * S_ + k0 + t;
      __syncthreads();
      if (t == 0) runningS += wtot[0] + wtot[1] + wtot[2] + wtot[3];
      __syncthreads();
    }
    int n = runningS;
    for (int j = n + t; j < S_; j += 256)   // pad FULL tail (safe gather rows)
      R[b * S_ + j] = b * S_;
    if (t == 0) { npadArr[b] = (n + 63) & ~63; narrArr[b] = n; }
    return;
  }

  // dtype self-detect: sample first 512 u16 of x (L1/L2-hot broadcast).
  __shared__ int scnt[4];
  {
    const unsigned short* xr = (const unsigned short*)x;
    unsigned short h = xr[2 * t];
    int e = (h >> 7) & 0xFF;
    unsigned long long bal = __ballot(e >= 100 && e <= 140);
    if ((t & 63) == 0) scnt[t >> 6] = __popcll(bal);
  }
  __syncthreads();
  const int is_bf = (scnt[0] + scnt[1] + scnt[2] + scnt[3] > 148) ? 1 : 0;
  if (bid == 4 && t == 0) *flag = is_bf;

  const int cb = bid - 4;
  if (cb < 3072) {                        // convx: 3072*256*8 = 6291456 elems
    int base = (cb * 256 + t) * 8;
    if (is_bf) {
      *(uintx4*)(Xb + base) = *(const uintx4*)((const __bf16*)x + base);
    } else {
      const float* xf = (const float*)x + base;
      f32x4 a = *(const f32x4*)xf;
      f32x4 c = *(const f32x4*)(xf + 4);
      __bf16 ov[8] = {(__bf16)a[0], (__bf16)a[1], (__bf16)a[2], (__bf16)a[3],
                      (__bf16)c[0], (__bf16)c[1], (__bf16)c[2], (__bf16)c[3]};
      *(uintx4*)(Xb + base) = *(uintx4*)ov;
    }
    return;
  }

  const int tb = cb - 3072;               // transpose tile / bias block index
  if (tb >= 577) return;

  if (tb == 576) {                        // biases: 2304 + 768 = 3072 scalars
    for (int i = t; i < 3072; i += 256) {
      if (i < NQKV) {
        int sel = i / 768, hd = i - sel * 768;
        const void* bsel = (sel == 0) ? bq : (sel == 1) ? bk : bv;
        biasP[i] = ldmixf(bsel, hd, is_bf);
      } else {
        biasO[i - NQKV] = ldmixf(bo, i - NQKV, is_bf);
      }
    }
    return;
  }

  // 64x64 LDS-tiled transpose. tl row pad +2 keeps 4B bank granularity:
  // column reads alias 2 lanes/bank (free per m136).
  __shared__ __bf16 tl[64][66];
  const int er  = t >> 2;                 // 0..63: input row within tile
  const int cg  = (t & 3) * 16;           // 16-elem chunk within row

  const void* src;                        // input, row-major [rows][cols]
  size_t ibase; int istride;              // elem index = ibase + row*istride + col
  __bf16* dst; int n0, c0out;             // output rows n0+dr, cols c0out+ec
  if (tb < 432) {                         // WbT: transpose W[h] (768e x 64d)
    int combo = tb / 12;                  // 0..35 = sel*12+h
    int e0 = (tb - combo * 12) * 64;
    int sel = combo / 12, h = combo - sel * 12;
    src = (sel == 0) ? Wq : (sel == 1) ? Wk : Wv;
    ibase = (size_t)(h * 768 + e0) * 64;  // rows: e (stride 64), cols: d
    istride = 64;
    dst = WbT; n0 = sel * 768 + h * 64; c0out = e0;
  } else {                                // WoT: transpose Wo (768k x 768n)
    int tj = tb - 432;                    // 0..143
    int r0 = (tj / 12) * 64;              // output-row block (n of Wo)
    int c0 = (tj - (tj / 12) * 12) * 64;  // output-col block (k of Wo)
    src = Wo;
    ibase = (size_t)c0 * 768 + r0;        // rows: k (stride 768), cols: n
    istride = 768;
    dst = WoT; n0 = r0; c0out = c0;
  }

  {
    size_t off = ibase + (size_t)er * istride + cg;
    if (is_bf) {
      bf16x8 a = *(const bf16x8*)((const __bf16*)src + off);
      bf16x8 bvv = *(const bf16x8*)((const __bf16*)src + off + 8);
      *(bf16x8*)(&tl[er][cg]) = a;
      *(bf16x8*)(&tl[er][cg + 8]) = bvv;
    } else {
      const float* sf = (const float*)src + off;
      f32x4 a = *(const f32x4*)sf;
      f32x4 bvv = *(const f32x4*)(sf + 4);
      f32x4 c = *(const f32x4*)(sf + 8);
      f32x4 d = *(const f32x4*)(sf + 12);
      __bf16 cv[16] = {(__bf16)a[0], (__bf16)a[1], (__bf16)a[2], (__bf16)a[3],
                       (__bf16)bvv[0], (__bf16)bvv[1], (__bf16)bvv[2], (__bf16)bvv[3],
                       (__bf16)c[0], (__bf16)c[1], (__bf16)c[2], (__bf16)c[3],
                       (__bf16)d[0], (__bf16)d[1], (__bf16)d[2], (__bf16)d[3]};
      *(bf16x8*)(&tl[er][cg]) = *(bf16x8*)cv;
      *(bf16x8*)(&tl[er][cg + 8]) = *(bf16x8*)(cv + 8);
    }
  }
  __syncthreads();
  {
    const int dr = t >> 2;                // output row within tile
    const int ec = (t & 3) * 16;          // output col chunk
    __bf16 ov[16];
#pragma unroll
    for (int j = 0; j < 16; ++j) ov[j] = tl[ec + j][dr];
    __bf16* po = dst + (size_t)(n0 + dr) * 768 + c0out + ec;
    *(uintx4*)po = *(uintx4*)ov;
    *(uintx4*)(po + 8) = *(uintx4*)(ov + 8);
  }
}

// ---------------- fused Q + K/V projection, 128x128 tiles (r15 best: 46.6us;
// r16's depth-1 dbuf REVERTED: HBM-priced loads ~900cy >> one tile of compute
// -> prefetch depth 1 hides <1/4 of latency while adding barrier+LDS cost). --
__global__ __launch_bounds__(256) void gemm_qkv(
    const __bf16* __restrict__ Xb,    // [8192][768]
    const __bf16* __restrict__ WbT,   // [2304][768]
    const float* __restrict__ biasP,  // [2304]
    const int* __restrict__ R,        // [B][2048] fully padded
    const int* __restrict__ npadArr,  // [B]
    __bf16* __restrict__ Qc,          // [8192][768]
    __bf16* __restrict__ Kc,          // [48][2048][64]
    __bf16* __restrict__ Vc)          // [48][512][256]
{
  __shared__ __align__(16) __bf16 As[128 * 32];
  __shared__ __align__(16) __bf16 Bs[128 * 32];
  const int t = threadIdx.x;
  const int wave = t >> 6, lane = t & 63;
  const int l15 = lane & 15, lq = lane >> 4;
  const int wm = (wave & 1) * 64;
  const int wn = (wave >> 1) * 64;

  const int bid = blockIdx.x;
  int m0, bn0, isQ, b = 0;
  int rowA0, rowA1;
  if (bid < 384) {
    isQ = 1;
    int mi = bid / 6, ni = bid - mi * 6;
    m0 = mi * 128; bn0 = ni * 128;
    rowA0 = m0 + (t >> 2);
    rowA1 = m0 + 64 + (t >> 2);
  } else {
    isQ = 0;
    int r2 = bid - 384;
    b = r2 / 192;
    int rr = r2 - b * 192;
    int mi = rr / 12, ni = rr - mi * 12;
    int np = npadArr[b];
    np = (np < 0) ? 0 : ((np > 2048) ? 2048 : np);   // poison-safe
    if (mi * 128 >= np) return;
    m0 = mi * 128;
    bn0 = 768 + ni * 128;
    rowA0 = R[b * S_ + m0 + (t >> 2)] & (M_ - 1);    // poison-safe
    rowA1 = R[b * S_ + m0 + 64 + (t >> 2)] & (M_ - 1);
  }
  const int c8 = (t & 3) << 3;
  const int brow0 = bn0 + (t >> 2);
  const int brow1 = bn0 + 64 + (t >> 2);

  const f32x4 z4 = {0.f, 0.f, 0.f, 0.f};
  f32x4 acc[4][4];
#pragma unroll
  for (int i = 0; i < 4; ++i)
#pragma unroll
    for (int j = 0; j < 4; ++j) acc[i][j] = z4;

  for (int k0 = 0; k0 < KDIM; k0 += 32) {
    __syncthreads();
    gl_lds16(Xb + (size_t)rowA0 * KDIM + k0 + c8, As + (size_t)wave * 512);
    gl_lds16(Xb + (size_t)rowA1 * KDIM + k0 + c8, As + (size_t)(2048 + wave * 512));
    gl_lds16(WbT + (size_t)brow0 * KDIM + k0 + c8, Bs + (size_t)wave * 512);
    gl_lds16(WbT + (size_t)brow1 * KDIM + k0 + c8, Bs + (size_t)(2048 + wave * 512));
    __syncthreads();
    bf16x8 af[4], bfr[4];
#pragma unroll
    for (int i = 0; i < 4; ++i) af[i]  = *(const bf16x8*)(As + (wm + i * 16 + l15) * 32 + lq * 8);
#pragma unroll
    for (int j = 0; j < 4; ++j) bfr[j] = *(const bf16x8*)(Bs + (wn + j * 16 + l15) * 32 + lq * 8);
#pragma unroll
    for (int i = 0; i < 4; ++i)
#pragma unroll
      for (int j = 0; j < 4; ++j)
        acc[i][j] = mfma16(af[i], bfr[j], acc[i][j]);
  }

#pragma unroll
  for (int j = 0; j < 4; ++j) {
    if (isQ) {
      int nn = bn0 + wn + j * 16 + l15;
      float bv = biasP[nn];
#pragma unroll
      for (int i = 0; i < 4; ++i) {
        int mbase = m0 + wm + i * 16 + lq * 4;
#pragma unroll
        for (int r = 0; r < 4; ++r)
          Qc[(size_t)(mbase + r) * 768 + nn] = (__bf16)(acc[i][j][r] + bv);
      }
    } else {
      int nn = (bn0 - 768) + wn + j * 16 + l15;   // col within 1536
      float bv = biasP[768 + nn];
      const int isK = (nn < 768);
      const int hh = (isK ? nn : nn - 768) >> 6;
      const int d  = nn & 63;
      const size_t bhh = (size_t)(b * H_ + hh);
#pragma unroll
      for (int i = 0; i < 4; ++i) {
        int jbase = m0 + wm + i * 16 + lq * 4;
#pragma unroll
        for (int r = 0; r < 4; ++r) {
          int jj = jbase + r;
          __bf16 ov = (__bf16)(acc[i][j][r] + bv);
          if (isK) Kc[(bhh * 2048 + jj) * 64 + d] = ov;
          else     Vc[(bhh * 512 + (jj >> 2)) * 256 + d * 4 + (jj & 3)] = ov;
        }
      }
    }
  }
}

// ---------------- output projection, 128x64 tiles (768 blocks = 3/CU) -------
// r16 change: 128x128 left gemm_out at 384 blocks = 1.5/CU -- worst TLP in
// the graph for a latency-bound drain loop. r0's 128x64 shape: 4 waves of
// 64x32, acc[4][2], grid 64x12 = 768 blocks = 3/CU (2x latency hiding).
__global__ __launch_bounds__(256) void gemm_out(
    const __bf16* __restrict__ A,     // [8192][768] attn out
    const __bf16* __restrict__ WoT,   // [768][768]
    const float* __restrict__ biasO,  // [768]
    void* __restrict__ C,             // [8192][768] fp32 or bf16 per flag
    const int* __restrict__ flag)
{
  __shared__ __align__(16) __bf16 As[128 * 32];
  __shared__ __align__(16) __bf16 Bs[64 * 32];
  const int obf = *flag;
  const int t = threadIdx.x;
  const int wave = t >> 6, lane = t & 63;
  const int l15 = lane & 15, lq = lane >> 4;
  const int wm = (wave & 1) * 64;
  const int wn = (wave >> 1) * 32;
  const int m0 = blockIdx.x * 128;
  const int n0 = blockIdx.y * 64;
  const int c8 = (t & 3) << 3;
  const int brow = t >> 2;                 // 0..63
  const int rowA0 = m0 + (t >> 2);
  const int rowA1 = m0 + 64 + (t >> 2);

  const f32x4 z4 = {0.f, 0.f, 0.f, 0.f};
  f32x4 acc[4][2];
#pragma unroll
  for (int i = 0; i < 4; ++i)
#pragma unroll
    for (int j = 0; j < 2; ++j) acc[i][j] = z4;

  for (int k0 = 0; k0 < KDIM; k0 += 32) {
    __syncthreads();
    gl_lds16(A + (size_t)rowA0 * KDIM + k0 + c8, As + (size_t)wave * 512);
    gl_lds16(A + (size_t)rowA1 * KDIM + k0 + c8, As + (size_t)(2048 + wave * 512));
    gl_lds16(WoT + (size_t)(n0 + brow) * KDIM + k0 + c8, Bs + (size_t)wave * 512);
    __syncthreads();
    bf16x8 af[4], bfr[2];
#pragma unroll
    for (int i = 0; i < 4; ++i) af[i]  = *(const bf16x8*)(As + (wm + i * 16 + l15) * 32 + lq * 8);
#pragma unroll
    for (int j = 0; j < 2; ++j) bfr[j] = *(const bf16x8*)(Bs + (wn + j * 16 + l15) * 32 + lq * 8);
#pragma unroll
    for (int i = 0; i < 4; ++i)
#pragma unroll
      for (int j = 0; j < 2; ++j)
        acc[i][j] = mfma16(af[i], bfr[j], acc[i][j]);
  }

#pragma unroll
  for (int j = 0; j < 2; ++j) {
    int n = n0 + wn + j * 16 + l15;
    float bv = biasO[n];
#pragma unroll
    for (int i = 0; i < 4; ++i) {
      int mbase = m0 + wm + i * 16 + lq * 4;
#pragma unroll
      for (int r = 0; r < 4; ++r) {
        size_t off = (size_t)(mbase + r) * 768 + n;
        float val = acc[i][j][r] + bv;
        if (obf) ((__bf16*)C)[off] = (__bf16)val;
        else     ((float*)C)[off]  = val;
      }
    }
  }
}

// ---------------- attention: round-8 best (QBLK=64, K/V LDS dbuf, counted
// vmcnt(4), swizzled K; 55.6us measured). --------------------------------
__global__ __launch_bounds__(256) void attn_kernel(
    const __bf16* __restrict__ Qc,     // [8192][768] (b,s,h,d)
    const __bf16* __restrict__ Kc,     // [48][2048][64]
    const __bf16* __restrict__ Vc,     // [48][512][256] quad layout
    const int* __restrict__ npadArr,   // [4] padded count
    const int* __restrict__ narrArr,   // [4] true count
    __bf16* __restrict__ Out)          // [8192][768] (b,s,h,d)
{
  __shared__ __align__(16) __bf16 Ks0[2][64 * 32];  // [buf][key][d 0..31] swz
  __shared__ __align__(16) __bf16 Ks1[2][64 * 32];  // [buf][key][d 32..63] swz
  __shared__ __align__(16) __bf16 Vt[2][16 * 256];  // [buf][key-quad][d][4 keys]

  const int t = threadIdx.x;
  const int w = t >> 6, lane = t & 63;
  const int l15 = lane & 15, qd = lane >> 4;
  const int bh = blockIdx.y;
  const int b = bh / H_, h = bh - b * H_;
  const int q0 = blockIdx.x * 64;
  int Skv = npadArr[b];
  Skv = (Skv < 0) ? 0 : ((Skv > 2048) ? 2048 : Skv);   // poison-safe
  int nb = narrArr[b];
  nb = (nb < 0) ? 0 : ((nb > Skv) ? Skv : nb);

  const __bf16* Qb = Qc + (size_t)b * S_ * E_ + h * 64;
  const __bf16* Kb = Kc + (size_t)bh * 2048 * 64;
  const __bf16* Vg = Vc + (size_t)bh * 512 * 256;

  bf16x8 qf[2];
  {
    int qrow = q0 + w * 16 + l15;
    qf[0] = *(const bf16x8*)(Qb + (size_t)qrow * E_ + qd * 8);
    qf[1] = *(const bf16x8*)(Qb + (size_t)qrow * E_ + 32 + qd * 8);
  }

  const f32x4 z4 = {0.f, 0.f, 0.f, 0.f};
  f32x4 o[4];
#pragma unroll
  for (int dt = 0; dt < 4; ++dt) o[dt] = z4;
  f32x4 ol = z4;

  const short one_bf = (short)0x3F80;
  const shortx4 ones4 = {one_bf, one_bf, one_bf, one_bf};

  const int skey = t >> 2;
  // source-side swizzle: chunk c_src = (t&3) ^ ((skey>>1)&3); skey>>1 = t>>3.
  const int sch  = (((t & 3) ^ ((t >> 3) & 3)) * 8);
  // read-side swizzle: chunk qd ^ ((l15>>1)&3), in elems (x8).
  const int qsw  = ((qd ^ ((l15 >> 1) & 3)) * 8);
  const float SC = 0.18033688011112042f;  // 0.125 * log2(e)

  const int nt = Skv >> 6;
  if (nt > 0) {
    gl_lds16(Kb + (size_t)skey * 64 + sch,      &Ks0[0][w * 512]);
    gl_lds16(Kb + (size_t)skey * 64 + 32 + sch, &Ks1[0][w * 512]);
    gl_lds16(Vg + t * 8,        &Vt[0][w * 512]);
    gl_lds16(Vg + 2048 + t * 8, &Vt[0][2048 + w * 512]);
  }

  for (int ti = 0; ti < nt; ++ti) {
    const int k0 = ti << 6;
    const int cur = ti & 1;
    if (ti + 1 < nt) {               // uniform branch (Skv uniform per block)
      const int nxt = cur ^ 1;
      const int kk = k0 + 64;
      gl_lds16(Kb + (size_t)(kk + skey) * 64 + sch,      &Ks0[nxt][w * 512]);
      gl_lds16(Kb + (size_t)(kk + skey) * 64 + 32 + sch, &Ks1[nxt][w * 512]);
      const __bf16* vsrc = Vg + ((size_t)(kk >> 2)) * 256;
      gl_lds16(vsrc + t * 8,        &Vt[nxt][w * 512]);
      gl_lds16(vsrc + 2048 + t * 8, &Vt[nxt][2048 + w * 512]);
      asm volatile("s_waitcnt vmcnt(4)" ::: "memory");  // tile cur done, nxt in flight
    } else {
      asm volatile("s_waitcnt vmcnt(0)" ::: "memory");
    }
    __builtin_amdgcn_s_barrier();

    const __bf16* K0 = Ks0[cur];
    const __bf16* K1 = Ks1[cur];
    const __bf16* Vb = Vt[cur];

    bf16x8 kf[4][2];
#pragma unroll
    for (int kt = 0; kt < 4; ++kt) {
      kf[kt][0] = *(const bf16x8*)(K0 + (kt * 16 + l15) * 32 + qsw);
      kf[kt][1] = *(const bf16x8*)(K1 + (kt * 16 + l15) * 32 + qsw);
    }
    shortx4 vf[4][4];
#pragma unroll
    for (int kt = 0; kt < 4; ++kt)
#pragma unroll
      for (int dt = 0; dt < 4; ++dt)
        vf[kt][dt] = *(const shortx4*)(Vb + (kt * 4 + qd) * 256 + (dt * 16 + l15) * 4);

    f32x4 ma[4];
    if (k0 + 64 <= nb) {             // all keys real: no mask (common path)
#pragma unroll
      for (int kt = 0; kt < 4; ++kt) ma[kt] = z4;
    } else {                         // boundary tile: pads start at nb
#pragma unroll
      for (int kt = 0; kt < 4; ++kt) {
        int kk = k0 + kt * 16 + qd * 4;
#pragma unroll
        for (int r = 0; r < 4; ++r)
          ma[kt][r] = (kk + r < nb) ? 0.f : -1.0e9f;
      }
    }

    {
      f32x4 s[4];
#pragma unroll
      for (int kt = 0; kt < 4; ++kt) {
        s[kt] = mfma16(kf[kt][0], qf[0], z4);
        s[kt] = mfma16(kf[kt][1], qf[1], s[kt]);
      }
      shortx4 pfr[4];
#pragma unroll
      for (int kt = 0; kt < 4; ++kt) {
        float p0 = __builtin_amdgcn_exp2f(__builtin_fmaf(s[kt][0], SC, ma[kt][0]));
        float p1 = __builtin_amdgcn_exp2f(__builtin_fmaf(s[kt][1], SC, ma[kt][1]));
        float p2 = __builtin_amdgcn_exp2f(__builtin_fmaf(s[kt][2], SC, ma[kt][2]));
        float p3 = __builtin_amdgcn_exp2f(__builtin_fmaf(s[kt][3], SC, ma[kt][3]));
        unsigned int lo16 = __builtin_amdgcn_perm(__builtin_bit_cast(unsigned int, p1),
                                                  __builtin_bit_cast(unsigned int, p0), 0x07060302u);
        unsigned int hi16 = __builtin_amdgcn_perm(__builtin_bit_cast(unsigned int, p3),
                                                  __builtin_bit_cast(unsigned int, p2), 0x07060302u);
        uintx2 u = {lo16, hi16};
        pfr[kt] = __builtin_bit_cast(shortx4, u);
      }
#pragma unroll
      for (int dt = 0; dt < 4; ++dt)
#pragma unroll
        for (int kt = 0; kt < 4; ++kt)
          o[dt] = mfma_pv(pfr[kt], vf[kt][dt], o[dt]);
#pragma unroll
      for (int kt = 0; kt < 4; ++kt)
        ol = mfma_pv(pfr[kt], ones4, ol);
    }

    __builtin_amdgcn_s_barrier();    // all waves done reading buf[cur] before
                                     // next iter's stage overwrites it
  }

#pragma unroll
  for (int dt = 0; dt < 4; ++dt)
#pragma unroll
    for (int r = 0; r < 4; ++r) {
      int qrow = q0 + w * 16 + qd * 4 + r;
      Out[(size_t)(b * S_ + qrow) * E_ + h * 64 + dt * 16 + l15] =
          (__bf16)(o[dt][r] / ol[r]);
    }
}

extern "C" void kernel_launch(void* const* d_in, const int* in_sizes, int n_in,
                              void* d_out, int out_size, void* d_ws, size_t ws_size,
                              hipStream_t stream) {
  const void* x  = d_in[0];
  const int* mask = (const int*)d_in[1];
  const void* Wq = d_in[2];
  const void* bq = d_in[3];
  const void* Wk = d_in[4];
  const void* bk = d_in[5];
  const void* Wv = d_in[6];
  const void* bv = d_in[7];
  const void* Wo = d_in[8];
  const void* bo = d_in[9];

  char* ws = (char*)d_ws;
  int*    flag  = (int*)(ws + 0);             // 256 B
  __bf16* Xb    = (__bf16*)(ws + 256);        // 12582912 -> 12583168
  __bf16* WbT   = (__bf16*)(ws + 12583168);   // 3538944  -> 16122112
  __bf16* WoT   = (__bf16*)(ws + 16122112);   // 1179648  -> 17301760
  float*  biasP = (float*)(ws + 17301760);    // 9216     -> 17310976
  float*  biasO = (float*)(ws + 17310976);    // 3072     -> 17314048
  __bf16* Qc    = (__bf16*)(ws + 17314048);   // 12582912 -> 29896960
  __bf16* Kc    = (__bf16*)(ws + 29896960);   // 12582912 -> 42479872
  __bf16* Vc    = (__bf16*)(ws + 42479872);   // 12582912 -> 55062784
  __bf16* attnO = (__bf16*)(ws + 55062784);   // 12582912 -> 67645696
  int*    Ridx  = (int*)(ws + 67645696);      // 32768    -> 67678464
  int*    npad  = (int*)(ws + 67711232);      // 16       -> 67711248
  int*    narr  = (int*)(ws + 67711248);      // 16       -> 67711264

  prep_kernel<<<dim3(3653), dim3(256), 0, stream>>>(
      x, mask, Wq, bq, Wk, bk, Wv, bv, Wo, bo,
      flag, Xb, WbT, WoT, biasP, biasO, Ridx, npad, narr);
  gemm_qkv<<<dim3(1152), dim3(256), 0, stream>>>(Xb, WbT, biasP, Ridx, npad, Qc, Kc, Vc);
  attn_kernel<<<dim3(32, 48), dim3(256), 0, stream>>>(Qc, Kc, Vc, npad, narr, attnO);
  gemm_out<<<dim3(64, 12), dim3(256), 0, stream>>>(attnO, WoT, biasO, d_out, flag);
}